// Round 5
// baseline (775.464 us; speedup 1.0000x reference)
//
#include <hip/hip_runtime.h>
#include <hip/hip_bf16.h>
#include <math.h>

#define BB 2
#define SS 1024
#define HH 2048
#define NHD 16
#define NOPE 128
#define ROPED 64
#define VDIM 128
#define QKD 192
#define QLR 1536
#define KVLR 512
#define EPSF 1e-5f
#define NCOMB 2176   // QLR + 576 kv + 64 pad

typedef __bf16 bf16x8 __attribute__((ext_vector_type(8)));
typedef float  f32x4  __attribute__((ext_vector_type(4)));

__device__ __forceinline__ void gload_lds16(const __bf16* g, __bf16* l) {
    __builtin_amdgcn_global_load_lds(
        (const __attribute__((address_space(1))) void*)g,
        (__attribute__((address_space(3))) void*)l, 16, 0, 0);
}

// ---------------------------------------------------------------------------
// MFMA bf16 GEMM: C[M,N] = A[M,K] @ B[N,K]^T (m97 structure, validated R3).
// ---------------------------------------------------------------------------
template<bool OUT_BF16>
__global__ __launch_bounds__(256, 2) void gemm_mfma(
    const __bf16* __restrict__ A, const __bf16* __restrict__ B, void* __restrict__ Cv,
    int M, int N, int K, int lda, int ldb, int ldc,
    long long sA, long long sB, long long sC)
{
    __shared__ __bf16 As[128][32];
    __shared__ __bf16 Bs[128][32];
    const __bf16* Ab = A + (long long)blockIdx.z * sA;
    const __bf16* Bb = B + (long long)blockIdx.z * sB;
    const int tid = threadIdx.x;
    const int w = tid >> 6, lane = tid & 63, quad = lane >> 4, ln = lane & 15;
    const int m0 = blockIdx.y * 128, n0 = blockIdx.x * 128;
    const int wm = (w >> 1) * 64, wn = (w & 1) * 64;
    const int srow = tid >> 2, schunk = (tid & 3) * 8;

    f32x4 acc[4][4];
#pragma unroll
    for (int i = 0; i < 4; ++i)
#pragma unroll
        for (int j = 0; j < 4; ++j) acc[i][j] = (f32x4){0.f, 0.f, 0.f, 0.f};

    const __bf16* gA0 = Ab + (size_t)(m0 + srow) * lda + schunk;
    const __bf16* gA1 = gA0 + (size_t)64 * lda;
    const __bf16* gB0 = Bb + (size_t)(n0 + srow) * ldb + schunk;
    const __bf16* gB1 = gB0 + (size_t)64 * ldb;
    __bf16* lA0 = &As[w * 16][0];
    __bf16* lA1 = &As[64 + w * 16][0];
    __bf16* lB0 = &Bs[w * 16][0];
    __bf16* lB1 = &Bs[64 + w * 16][0];

    for (int k0 = 0; k0 < K; k0 += 32) {
        __syncthreads();
        gload_lds16(gA0 + k0, lA0);
        gload_lds16(gA1 + k0, lA1);
        gload_lds16(gB0 + k0, lB0);
        gload_lds16(gB1 + k0, lB1);
        __syncthreads();
        bf16x8 af[4], bfr[4];
#pragma unroll
        for (int mi = 0; mi < 4; ++mi)
            af[mi] = *(const bf16x8*)&As[wm + mi * 16 + ln][quad * 8];
#pragma unroll
        for (int ni = 0; ni < 4; ++ni)
            bfr[ni] = *(const bf16x8*)&Bs[wn + ni * 16 + ln][quad * 8];
#pragma unroll
        for (int mi = 0; mi < 4; ++mi)
#pragma unroll
            for (int ni = 0; ni < 4; ++ni)
                acc[mi][ni] = __builtin_amdgcn_mfma_f32_16x16x32_bf16(
                    af[mi], bfr[ni], acc[mi][ni], 0, 0, 0);
    }
    if (OUT_BF16) {
        __bf16* Cb = (__bf16*)Cv + (long long)blockIdx.z * sC;
#pragma unroll
        for (int mi = 0; mi < 4; ++mi)
#pragma unroll
            for (int r = 0; r < 4; ++r) {
                size_t row = (size_t)(m0 + wm + mi * 16 + quad * 4 + r);
#pragma unroll
                for (int ni = 0; ni < 4; ++ni)
                    Cb[row * ldc + (n0 + wn + ni * 16 + ln)] = (__bf16)acc[mi][ni][r];
            }
    } else {
        float* Cb = (float*)Cv + (long long)blockIdx.z * sC;
#pragma unroll
        for (int mi = 0; mi < 4; ++mi)
#pragma unroll
            for (int r = 0; r < 4; ++r) {
                size_t row = (size_t)(m0 + wm + mi * 16 + quad * 4 + r);
#pragma unroll
                for (int ni = 0; ni < 4; ++ni)
                    Cb[row * ldc + (n0 + wn + ni * 16 + ln)] = acc[mi][ni][r];
            }
    }
}

// ---------------------------------------------------------------------------
// Cast helpers
// ---------------------------------------------------------------------------
__global__ __launch_bounds__(256) void castf2b(const float* __restrict__ in,
                                               __bf16* __restrict__ out, int n)
{
    int i = (blockIdx.x * 256 + threadIdx.x) * 4;
    if (i < n) {
        float4 v = *(const float4*)(in + i);
        out[i] = (__bf16)v.x; out[i + 1] = (__bf16)v.y;
        out[i + 2] = (__bf16)v.z; out[i + 3] = (__bf16)v.w;
    }
}

// combined [w_qa(1536); w_kva(576); pad(64)] x 2048 -> bf16
__global__ __launch_bounds__(256) void cast_comb(const float* __restrict__ wqa,
                                                 const float* __restrict__ wkva,
                                                 __bf16* __restrict__ out)
{
    int idx = (blockIdx.x * 256 + threadIdx.x) * 4;
    int row = idx >> 11, col = idx & 2047;
    const float* src;
    if (row < 1536)      src = wqa + (size_t)row * 2048 + col;
    else if (row < 2112) src = wkva + (size_t)(row - 1536) * 2048 + col;
    else {
        out[idx] = (__bf16)0.f; out[idx + 1] = (__bf16)0.f;
        out[idx + 2] = (__bf16)0.f; out[idx + 3] = (__bf16)0.f;
        return;
    }
    float4 v = *(const float4*)src;
    out[idx] = (__bf16)v.x; out[idx + 1] = (__bf16)v.y;
    out[idx + 2] = (__bf16)v.z; out[idx + 3] = (__bf16)v.w;
}

// batched transpose-cast: in[z][R][C] fp32 -> out[z][C][R] bf16
__global__ __launch_bounds__(256) void transpose_cast(const float* __restrict__ in,
                                                      __bf16* __restrict__ out,
                                                      int R, int C)
{
    __shared__ float t[32][33];
    in  += (size_t)blockIdx.z * R * C;
    out += (size_t)blockIdx.z * R * C;
    int c0 = blockIdx.x * 32, r0 = blockIdx.y * 32;
    int tx = threadIdx.x & 31, ty = threadIdx.x >> 5;
#pragma unroll
    for (int i = 0; i < 4; ++i) {
        int r = ty + i * 8;
        t[r][tx] = in[(size_t)(r0 + r) * C + c0 + tx];
    }
    __syncthreads();
#pragma unroll
    for (int i = 0; i < 4; ++i) {
        int rr = ty + i * 8;
        out[(size_t)(c0 + rr) * R + r0 + tx] = (__bf16)t[tx][rr];
    }
}

// Kc[b][k][f<512] bf16 -> Vt[b][f][k] bf16 (key-contiguous V)
__global__ __launch_bounds__(256) void transpose_kc(const __bf16* __restrict__ Kc,
                                                    __bf16* __restrict__ Vt)
{
    __shared__ __bf16 t[32][33];
    int b = blockIdx.z;
    int k0 = blockIdx.x * 32, f0 = blockIdx.y * 32;
    int tx = threadIdx.x & 31, ty = threadIdx.x >> 5;   // ty 0..7
    const __bf16* src = Kc + (size_t)b * SS * 576;
#pragma unroll
    for (int i = 0; i < 4; ++i)
        t[ty + i * 8][tx] = src[(size_t)(k0 + ty + i * 8) * 576 + f0 + tx];
    __syncthreads();
    __bf16* dst = Vt + (size_t)b * 512 * 1024;
#pragma unroll
    for (int i = 0; i < 4; ++i)
        dst[(size_t)(f0 + ty + i * 8) * 1024 + k0 + tx] = t[tx][ty + i * 8];
}

// ---------------------------------------------------------------------------
// LayerNorm fp32 in (row stride ldx) -> bf16 out (row stride N).
// ---------------------------------------------------------------------------
__global__ __launch_bounds__(256) void ln_kernel(const float* __restrict__ x,
                                                 const float* __restrict__ w,
                                                 __bf16* __restrict__ y, int N, int ldx)
{
    long long row = blockIdx.x;
    const float* xr = x + row * ldx;
    __bf16* yr = y + row * N;
    int tid = threadIdx.x;
    float s = 0.f, ss = 0.f;
    for (int i = tid; i < N; i += 256) { float v = xr[i]; s += v; ss += v * v; }
#pragma unroll
    for (int off = 32; off > 0; off >>= 1) { s += __shfl_down(s, off); ss += __shfl_down(ss, off); }
    __shared__ float rs[4], rss[4];
    __shared__ float smean, sinv;
    int wave = tid >> 6, lane = tid & 63;
    if (lane == 0) { rs[wave] = s; rss[wave] = ss; }
    __syncthreads();
    if (tid == 0) {
        float S = rs[0] + rs[1] + rs[2] + rs[3];
        float Q = rss[0] + rss[1] + rss[2] + rss[3];
        float mean = S / N;
        float var = Q / N - mean * mean;
        smean = mean; sinv = rsqrtf(var + EPSF);
    }
    __syncthreads();
    float mean = smean, inv = sinv;
    for (int i = tid; i < N; i += 256) yr[i] = (__bf16)((xr[i] - mean) * inv * w[i]);
}

// ---------------------------------------------------------------------------
// Per-token prep: Kc[row] = bf16(concat(LN(kva[:512])*w, rope(kva[512:576])))
// kva row stride ld; rope q_pe in place inside bf16 q.
// ---------------------------------------------------------------------------
__global__ __launch_bounds__(256) void prep_kernel(
    const float* __restrict__ kva, int ld, const float* __restrict__ kvw,
    const float* __restrict__ cosb, const float* __restrict__ sinb,
    __bf16* __restrict__ Kc, __bf16* __restrict__ q)
{
    long long row = blockIdx.x;
    const float* kr = kva + row * ld;
    const float* cr = cosb + row * ROPED;
    const float* sr = sinb + row * ROPED;
    int tid = threadIdx.x;
    float v0 = kr[tid], v1 = kr[tid + 256];
    float s = v0 + v1, ss = v0 * v0 + v1 * v1;
#pragma unroll
    for (int off = 32; off > 0; off >>= 1) { s += __shfl_down(s, off); ss += __shfl_down(ss, off); }
    __shared__ float rs[4], rss[4];
    __shared__ float smean, sinv;
    int wave = tid >> 6, lane = tid & 63;
    if (lane == 0) { rs[wave] = s; rss[wave] = ss; }
    __syncthreads();
    if (tid == 0) {
        float S = rs[0] + rs[1] + rs[2] + rs[3];
        float Q = rss[0] + rss[1] + rss[2] + rss[3];
        float mean = S / KVLR;
        float var = Q / KVLR - mean * mean;
        smean = mean; sinv = rsqrtf(var + EPSF);
    }
    __syncthreads();
    float mean = smean, inv = sinv;
    __bf16* kc = Kc + row * 576;
    kc[tid]       = (__bf16)((v0 - mean) * inv * kvw[tid]);
    kc[tid + 256] = (__bf16)((v1 - mean) * inv * kvw[tid + 256]);
    if (tid < 32) {
        float x1 = kr[KVLR + tid], x2 = kr[KVLR + 32 + tid];
        kc[512 + tid]      = (__bf16)(x1 * cr[tid] - x2 * sr[tid]);
        kc[512 + 32 + tid] = (__bf16)(x2 * cr[32 + tid] + x1 * sr[32 + tid]);
    }
    __bf16* qr = q + row * (NHD * QKD);
#pragma unroll
    for (int j = 0; j < 2; ++j) {
        int idx = tid + j * 256;
        int h = idx >> 5, p = idx & 31;
        __bf16* base = qr + h * QKD + NOPE;
        float x1 = (float)base[p], x2 = (float)base[32 + p];
        base[p]      = (__bf16)(x1 * cr[p] - x2 * sr[p]);
        base[32 + p] = (__bf16)(x2 * cr[32 + p] + x1 * sr[32 + p]);
    }
}

// ---------------------------------------------------------------------------
// Qc bf16 [B][NH][S][576] = concat(qlat_b, roped q_pe bf16)
// ---------------------------------------------------------------------------
__global__ __launch_bounds__(256) void qcast_kernel(
    const __bf16* __restrict__ qlat, const __bf16* __restrict__ qb,
    __bf16* __restrict__ Qc)
{
    long long row = blockIdx.x;           // b*S + s
    int b = (int)(row >> 10), s = (int)(row & 1023);
    int tid = threadIdx.x;
    for (int i = tid; i < NHD * 576; i += 256) {
        int h = i / 576, c = i - h * 576;
        __bf16 v = (c < 512) ? qlat[row * (NHD * 512) + h * 512 + c]
                             : qb[row * (NHD * QKD) + h * QKD + NOPE + (c - 512)];
        Qc[(((size_t)(b * NHD + h)) * SS + s) * 576 + c] = v;
    }
}

// ---------------------------------------------------------------------------
// Flash MLA v4: direct-global K/V fragment loads (L2-resident), NO LDS
// staging, NO barriers. Perfect load balance: block = q-tile pair
// (15-pair, pair) -> exactly 36 k-tiles per block; 256 identical blocks.
// Per-wave skip of fully-masked diagonal tiles.
// ---------------------------------------------------------------------------
__global__ __launch_bounds__(256) void flash_kernel(
    const __bf16* __restrict__ Qc, const __bf16* __restrict__ Kc,
    const __bf16* __restrict__ Vt, __bf16* __restrict__ ctx)
{
    __shared__ __bf16 Pb[4][16][32];   // per-wave P transpose (no barrier)
    const int pair = blockIdx.x;       // 0..7
    const int h = blockIdx.y, b = blockIdx.z;
    const int tid = threadIdx.x;
    const int w = tid >> 6, lane = tid & 63, quad = lane >> 4, ln = lane & 15;
    const size_t kbase = (size_t)b * SS * 576;
    const size_t vbase = (size_t)b * 512 * 1024;
    const float SCL = 0.07216878364870323f * 1.4426950408889634f;  // scale*log2e

#pragma unroll 1
    for (int pi = 0; pi < 2; ++pi) {
        const int qt = pi ? pair : (15 - pair);   // long sub-problem first
        const int q0 = qt * 64;
        const int ktc = q0 / 32 + 2;
        const int myqmax = q0 + w * 16 + 15;      // this wave's last q row

        const size_t qoff = ((size_t)(b * NHD + h) * SS + (size_t)(q0 + w * 16 + ln)) * 576;
        bf16x8 qf[18];
#pragma unroll
        for (int kc = 0; kc < 18; ++kc)
            qf[kc] = *(const bf16x8*)(Qc + qoff + kc * 32 + quad * 8);

        f32x4 O[32];
#pragma unroll
        for (int nt = 0; nt < 32; ++nt) O[nt] = (f32x4){0.f, 0.f, 0.f, 0.f};
        float mrun[4] = {-1e30f, -1e30f, -1e30f, -1e30f};
        float lrun[4] = {0.f, 0.f, 0.f, 0.f};

#pragma unroll 1
        for (int kt = 0; kt < ktc; ++kt) {
            const int k0 = kt * 32;
            if (k0 > myqmax) continue;            // wave-uniform: fully masked

            // ---- scores: K fragments straight from global (L2) ----
            const __bf16* kp0 = Kc + kbase + (size_t)(k0 + ln) * 576 + quad * 8;
            const __bf16* kp1 = kp0 + (size_t)16 * 576;
            f32x4 s0 = (f32x4){0.f, 0.f, 0.f, 0.f};
            f32x4 s1 = (f32x4){0.f, 0.f, 0.f, 0.f};
#pragma unroll
            for (int kc = 0; kc < 18; ++kc) {
                bf16x8 kf0 = *(const bf16x8*)(kp0 + kc * 32);
                bf16x8 kf1 = *(const bf16x8*)(kp1 + kc * 32);
                s0 = __builtin_amdgcn_mfma_f32_16x16x32_bf16(qf[kc], kf0, s0, 0, 0, 0);
                s1 = __builtin_amdgcn_mfma_f32_16x16x32_bf16(qf[kc], kf1, s1, 0, 0, 0);
            }

            // ---- online softmax (rows quad*4+r, cols ln / 16+ln) ----
            const bool diag = (k0 + 31 > q0 + w * 16);
            float alpha[4];
#pragma unroll
            for (int r = 0; r < 4; ++r) {
                float v0 = s0[r] * SCL, v1 = s1[r] * SCL;
                if (diag) {
                    int qrow = q0 + w * 16 + quad * 4 + r;
                    if (k0 + ln > qrow)      v0 = -1e30f;
                    if (k0 + 16 + ln > qrow) v1 = -1e30f;
                }
                float mx = fmaxf(v0, v1);
#pragma unroll
                for (int off = 1; off < 16; off <<= 1) mx = fmaxf(mx, __shfl_xor(mx, off));
                float mnew = fmaxf(mrun[r], mx);
                alpha[r] = __builtin_amdgcn_exp2f(mrun[r] - mnew);
                float p0 = __builtin_amdgcn_exp2f(v0 - mnew);
                float p1 = __builtin_amdgcn_exp2f(v1 - mnew);
                float rsum = p0 + p1;
#pragma unroll
                for (int off = 1; off < 16; off <<= 1) rsum += __shfl_xor(rsum, off);
                lrun[r] = lrun[r] * alpha[r] + rsum;
                mrun[r] = mnew;
                Pb[w][quad * 4 + r][ln]      = (__bf16)p0;
                Pb[w][quad * 4 + r][16 + ln] = (__bf16)p1;
            }
#pragma unroll
            for (int nt = 0; nt < 32; ++nt) {
#pragma unroll
                for (int r = 0; r < 4; ++r) O[nt][r] *= alpha[r];
            }
            bf16x8 pf = *(const bf16x8*)&Pb[w][ln][quad * 8];  // per-wave lgkm wait

            // ---- PV: V^T fragments straight from global (L2) ----
            const __bf16* vp = Vt + vbase + (size_t)ln * 1024 + k0 + quad * 8;
#pragma unroll
            for (int nt = 0; nt < 32; ++nt) {
                bf16x8 vf = *(const bf16x8*)(vp + (size_t)(nt * 16) * 1024);
                O[nt] = __builtin_amdgcn_mfma_f32_16x16x32_bf16(pf, vf, O[nt], 0, 0, 0);
            }
        }

        // ---- epilogue for this q-tile ----
#pragma unroll
        for (int r = 0; r < 4; ++r) {
            float inv = 1.f / lrun[r];
            size_t row = (size_t)b * SS + (size_t)(q0 + w * 16 + quad * 4 + r);
            __bf16* op = ctx + (row * NHD + h) * 512;
#pragma unroll
            for (int nt = 0; nt < 32; ++nt)
                op[nt * 16 + ln] = (__bf16)(O[nt][r] * inv);
        }
    }
}

// ---------------------------------------------------------------------------
extern "C" void kernel_launch(void* const* d_in, const int* in_sizes, int n_in,
                              void* d_out, int out_size, void* d_ws, size_t ws_size,
                              hipStream_t stream)
{
    const float* hidden    = (const float*)d_in[0];
    const float* cosb      = (const float*)d_in[1];
    const float* sinb      = (const float*)d_in[2];
    const float* w_qa      = (const float*)d_in[3];
    const float* q_a_ln_w  = (const float*)d_in[4];
    const float* w_qb      = (const float*)d_in[5];
    const float* w_kva     = (const float*)d_in[6];
    const float* kv_a_ln_w = (const float*)d_in[7];
    const float* W_UK_T    = (const float*)d_in[8];
    const float* W_UV      = (const float*)d_in[9];
    const float* w_o       = (const float*)d_in[10];
    float* out = (float*)d_out;

    const int M = BB * SS;  // 2048
    // fp32: combined qa|kva activation (M x 2176) = 17.8 MB
    float* qakva = (float*)d_ws;
    // bf16 region
    __bf16* Xb    = (__bf16*)(qakva + (size_t)M * NCOMB);
    __bf16* qab   = Xb    + (size_t)M * HH;           // M*1536
    __bf16* qb    = qab   + (size_t)M * QLR;          // M*3072
    __bf16* Kc    = qb    + (size_t)M * NHD * QKD;    // M*576
    __bf16* Qc    = Kc    + (size_t)M * 576;          // M*9216
    __bf16* qlatb = Qc    + (size_t)M * NHD * 576;    // M*8192
    __bf16* ctxb  = qlatb + (size_t)M * NHD * KVLR;   // M*8192
    __bf16* ohb   = ctxb  + (size_t)M * NHD * KVLR;   // M*2048
    __bf16* Vt    = ohb   + (size_t)M * HH;           // 2*512*1024
    __bf16* w_cmb = Vt    + (size_t)BB * 512 * SS;    // 2176*2048
    __bf16* w_qbb = w_cmb + (size_t)NCOMB * HH;       // 3072*1536
    __bf16* Wkb   = w_qbb + (size_t)NHD * QKD * QLR;  // 16*512*128
    __bf16* Wvb   = Wkb   + (size_t)NHD * KVLR * NOPE;// 16*128*512
    __bf16* w_ob  = Wvb   + (size_t)NHD * VDIM * KVLR;// 2048*2048

    dim3 blk(256);

    // --- casts ---
    castf2b<<<dim3((M * HH) / 1024), blk, 0, stream>>>(hidden, Xb, M * HH);
    cast_comb<<<dim3((NCOMB * HH) / 1024), blk, 0, stream>>>(w_qa, w_kva, w_cmb);
    castf2b<<<dim3((NHD * QKD * QLR) / 1024), blk, 0, stream>>>(w_qb, w_qbb, NHD * QKD * QLR);
    castf2b<<<dim3((HH * HH) / 1024), blk, 0, stream>>>(w_o, w_ob, HH * HH);
    transpose_cast<<<dim3(KVLR / 32, NOPE / 32, NHD), blk, 0, stream>>>(W_UK_T, Wkb, NOPE, KVLR);
    transpose_cast<<<dim3(VDIM / 32, KVLR / 32, NHD), blk, 0, stream>>>(W_UV, Wvb, KVLR, VDIM);

    // 1+4 fused: qakva = Xb @ [w_qa; w_kva]^T   (2048 x 2176 x 2048)
    gemm_mfma<false><<<dim3(NCOMB / 128, M / 128, 1), blk, 0, stream>>>(
        Xb, w_cmb, qakva, M, NCOMB, HH, HH, HH, NCOMB, 0, 0, 0);
    // 2. qab = bf16(LN(qakva[:, :1536]))
    ln_kernel<<<dim3(M), blk, 0, stream>>>(qakva, q_a_ln_w, qab, QLR, NCOMB);
    // 3. qb = qab @ w_qb^T (bf16)              (2048 x 3072 x 1536)
    gemm_mfma<true><<<dim3(NHD * QKD / 128, M / 128, 1), blk, 0, stream>>>(
        qab, w_qbb, qb, M, NHD * QKD, QLR, QLR, QLR, NHD * QKD, 0, 0, 0);
    // 5. Kc = [LN(kv_c), rope(k_pe)] bf16; rope q_pe in place (bf16)
    prep_kernel<<<dim3(M), blk, 0, stream>>>(qakva + QLR, NCOMB, kv_a_ln_w,
                                             cosb, sinb, Kc, qb);
    // 5b. Vt = transpose(Kc[:, :512])
    transpose_kc<<<dim3(SS / 32, 512 / 32, BB), blk, 0, stream>>>(Kc, Vt);
    // 6. qlatb[h] = q_nope[h] @ Wkb[h]^T       (16 x [2048 x 512 x 128])
    gemm_mfma<true><<<dim3(KVLR / 128, M / 128, NHD), blk, 0, stream>>>(
        qb, Wkb, qlatb, M, KVLR, NOPE,
        NHD * QKD, NOPE, NHD * KVLR,
        (long long)QKD, (long long)KVLR * NOPE, (long long)KVLR);
    // 7. Qc = concat(qlatb, roped q_pe), layout [B,NH,S,576]
    qcast_kernel<<<dim3(M), blk, 0, stream>>>(qlatb, qb, Qc);
    // 8. flash attention -> ctx bf16 [B,S,NH*512]; 256 perfectly-balanced blocks
    flash_kernel<<<dim3(8, NHD, BB), blk, 0, stream>>>(Qc, Kc, Vt, ctxb);
    // 9. ohb[h] = ctx[h] @ Wvb[h]^T            (16 x [2048 x 128 x 512])
    gemm_mfma<true><<<dim3(VDIM / 128, M / 128, NHD), blk, 0, stream>>>(
        ctxb, Wvb, ohb, M, VDIM, KVLR,
        NHD * KVLR, KVLR, NHD * VDIM,
        (long long)KVLR, (long long)VDIM * KVLR, (long long)VDIM);
    // 10. out = ohb @ w_o^T (fp32)             (2048 x 2048 x 2048)
    gemm_mfma<false><<<dim3(HH / 128, M / 128, 1), blk, 0, stream>>>(
        ohb, w_ob, out, M, HH, NHD * VDIM, NHD * VDIM, NHD * VDIM, HH, 0, 0, 0);
}

// Round 6
// 561.279 us; speedup vs baseline: 1.3816x; 1.3816x over previous
//
#include <hip/hip_runtime.h>
#include <hip/hip_bf16.h>
#include <math.h>

#define BB 2
#define SS 1024
#define HH 2048
#define NHD 16
#define NOPE 128
#define ROPED 64
#define VDIM 128
#define QKD 192
#define QLR 1536
#define KVLR 512
#define EPSF 1e-5f
#define NCOMB 2176   // QLR + 576 kv + 64 pad

typedef __bf16 bf16x8 __attribute__((ext_vector_type(8)));
typedef float  f32x4  __attribute__((ext_vector_type(4)));

__device__ __forceinline__ void gload_lds16(const __bf16* g, __bf16* l) {
    __builtin_amdgcn_global_load_lds(
        (const __attribute__((address_space(1))) void*)g,
        (__attribute__((address_space(3))) void*)l, 16, 0, 0);
}

// ---------------------------------------------------------------------------
// MFMA bf16 GEMM: C[M,N] = A[M,K] @ B[N,K]^T (m97 structure, validated R3).
// ---------------------------------------------------------------------------
template<bool OUT_BF16>
__global__ __launch_bounds__(256, 2) void gemm_mfma(
    const __bf16* __restrict__ A, const __bf16* __restrict__ B, void* __restrict__ Cv,
    int M, int N, int K, int lda, int ldb, int ldc,
    long long sA, long long sB, long long sC)
{
    __shared__ __bf16 As[128][32];
    __shared__ __bf16 Bs[128][32];
    const __bf16* Ab = A + (long long)blockIdx.z * sA;
    const __bf16* Bb = B + (long long)blockIdx.z * sB;
    const int tid = threadIdx.x;
    const int w = tid >> 6, lane = tid & 63, quad = lane >> 4, ln = lane & 15;
    const int m0 = blockIdx.y * 128, n0 = blockIdx.x * 128;
    const int wm = (w >> 1) * 64, wn = (w & 1) * 64;
    const int srow = tid >> 2, schunk = (tid & 3) * 8;

    f32x4 acc[4][4];
#pragma unroll
    for (int i = 0; i < 4; ++i)
#pragma unroll
        for (int j = 0; j < 4; ++j) acc[i][j] = (f32x4){0.f, 0.f, 0.f, 0.f};

    const __bf16* gA0 = Ab + (size_t)(m0 + srow) * lda + schunk;
    const __bf16* gA1 = gA0 + (size_t)64 * lda;
    const __bf16* gB0 = Bb + (size_t)(n0 + srow) * ldb + schunk;
    const __bf16* gB1 = gB0 + (size_t)64 * ldb;
    __bf16* lA0 = &As[w * 16][0];
    __bf16* lA1 = &As[64 + w * 16][0];
    __bf16* lB0 = &Bs[w * 16][0];
    __bf16* lB1 = &Bs[64 + w * 16][0];

    for (int k0 = 0; k0 < K; k0 += 32) {
        __syncthreads();
        gload_lds16(gA0 + k0, lA0);
        gload_lds16(gA1 + k0, lA1);
        gload_lds16(gB0 + k0, lB0);
        gload_lds16(gB1 + k0, lB1);
        __syncthreads();
        bf16x8 af[4], bfr[4];
#pragma unroll
        for (int mi = 0; mi < 4; ++mi)
            af[mi] = *(const bf16x8*)&As[wm + mi * 16 + ln][quad * 8];
#pragma unroll
        for (int ni = 0; ni < 4; ++ni)
            bfr[ni] = *(const bf16x8*)&Bs[wn + ni * 16 + ln][quad * 8];
#pragma unroll
        for (int mi = 0; mi < 4; ++mi)
#pragma unroll
            for (int ni = 0; ni < 4; ++ni)
                acc[mi][ni] = __builtin_amdgcn_mfma_f32_16x16x32_bf16(
                    af[mi], bfr[ni], acc[mi][ni], 0, 0, 0);
    }
    if (OUT_BF16) {
        __bf16* Cb = (__bf16*)Cv + (long long)blockIdx.z * sC;
#pragma unroll
        for (int mi = 0; mi < 4; ++mi)
#pragma unroll
            for (int r = 0; r < 4; ++r) {
                size_t row = (size_t)(m0 + wm + mi * 16 + quad * 4 + r);
#pragma unroll
                for (int ni = 0; ni < 4; ++ni)
                    Cb[row * ldc + (n0 + wn + ni * 16 + ln)] = (__bf16)acc[mi][ni][r];
            }
    } else {
        float* Cb = (float*)Cv + (long long)blockIdx.z * sC;
#pragma unroll
        for (int mi = 0; mi < 4; ++mi)
#pragma unroll
            for (int r = 0; r < 4; ++r) {
                size_t row = (size_t)(m0 + wm + mi * 16 + quad * 4 + r);
#pragma unroll
                for (int ni = 0; ni < 4; ++ni)
                    Cb[row * ldc + (n0 + wn + ni * 16 + ln)] = acc[mi][ni][r];
            }
    }
}

// ---------------------------------------------------------------------------
// Cast helpers
// ---------------------------------------------------------------------------
__global__ __launch_bounds__(256) void castf2b(const float* __restrict__ in,
                                               __bf16* __restrict__ out, int n)
{
    int i = (blockIdx.x * 256 + threadIdx.x) * 4;
    if (i < n) {
        float4 v = *(const float4*)(in + i);
        out[i] = (__bf16)v.x; out[i + 1] = (__bf16)v.y;
        out[i + 2] = (__bf16)v.z; out[i + 3] = (__bf16)v.w;
    }
}

// combined [w_qa(1536); w_kva(576); pad(64)] x 2048 -> bf16
__global__ __launch_bounds__(256) void cast_comb(const float* __restrict__ wqa,
                                                 const float* __restrict__ wkva,
                                                 __bf16* __restrict__ out)
{
    int idx = (blockIdx.x * 256 + threadIdx.x) * 4;
    int row = idx >> 11, col = idx & 2047;
    const float* src;
    if (row < 1536)      src = wqa + (size_t)row * 2048 + col;
    else if (row < 2112) src = wkva + (size_t)(row - 1536) * 2048 + col;
    else {
        out[idx] = (__bf16)0.f; out[idx + 1] = (__bf16)0.f;
        out[idx + 2] = (__bf16)0.f; out[idx + 3] = (__bf16)0.f;
        return;
    }
    float4 v = *(const float4*)src;
    out[idx] = (__bf16)v.x; out[idx + 1] = (__bf16)v.y;
    out[idx + 2] = (__bf16)v.z; out[idx + 3] = (__bf16)v.w;
}

// batched transpose-cast: in[z][R][C] fp32 -> out[z][C][R] bf16
__global__ __launch_bounds__(256) void transpose_cast(const float* __restrict__ in,
                                                      __bf16* __restrict__ out,
                                                      int R, int C)
{
    __shared__ float t[32][33];
    in  += (size_t)blockIdx.z * R * C;
    out += (size_t)blockIdx.z * R * C;
    int c0 = blockIdx.x * 32, r0 = blockIdx.y * 32;
    int tx = threadIdx.x & 31, ty = threadIdx.x >> 5;
#pragma unroll
    for (int i = 0; i < 4; ++i) {
        int r = ty + i * 8;
        t[r][tx] = in[(size_t)(r0 + r) * C + c0 + tx];
    }
    __syncthreads();
#pragma unroll
    for (int i = 0; i < 4; ++i) {
        int rr = ty + i * 8;
        out[(size_t)(c0 + rr) * R + r0 + tx] = (__bf16)t[tx][rr];
    }
}

// Kc[b][k][f<512] bf16 -> Vt[b][f][k] bf16 (key-contiguous V)
__global__ __launch_bounds__(256) void transpose_kc(const __bf16* __restrict__ Kc,
                                                    __bf16* __restrict__ Vt)
{
    __shared__ __bf16 t[32][33];
    int b = blockIdx.z;
    int k0 = blockIdx.x * 32, f0 = blockIdx.y * 32;
    int tx = threadIdx.x & 31, ty = threadIdx.x >> 5;   // ty 0..7
    const __bf16* src = Kc + (size_t)b * SS * 576;
#pragma unroll
    for (int i = 0; i < 4; ++i)
        t[ty + i * 8][tx] = src[(size_t)(k0 + ty + i * 8) * 576 + f0 + tx];
    __syncthreads();
    __bf16* dst = Vt + (size_t)b * 512 * 1024;
#pragma unroll
    for (int i = 0; i < 4; ++i)
        dst[(size_t)(f0 + ty + i * 8) * 1024 + k0 + tx] = t[tx][ty + i * 8];
}

// ---------------------------------------------------------------------------
// LayerNorm fp32 in (row stride ldx) -> bf16 out (row stride N).
// ---------------------------------------------------------------------------
__global__ __launch_bounds__(256) void ln_kernel(const float* __restrict__ x,
                                                 const float* __restrict__ w,
                                                 __bf16* __restrict__ y, int N, int ldx)
{
    long long row = blockIdx.x;
    const float* xr = x + row * ldx;
    __bf16* yr = y + row * N;
    int tid = threadIdx.x;
    float s = 0.f, ss = 0.f;
    for (int i = tid; i < N; i += 256) { float v = xr[i]; s += v; ss += v * v; }
#pragma unroll
    for (int off = 32; off > 0; off >>= 1) { s += __shfl_down(s, off); ss += __shfl_down(ss, off); }
    __shared__ float rs[4], rss[4];
    __shared__ float smean, sinv;
    int wave = tid >> 6, lane = tid & 63;
    if (lane == 0) { rs[wave] = s; rss[wave] = ss; }
    __syncthreads();
    if (tid == 0) {
        float S = rs[0] + rs[1] + rs[2] + rs[3];
        float Q = rss[0] + rss[1] + rss[2] + rss[3];
        float mean = S / N;
        float var = Q / N - mean * mean;
        smean = mean; sinv = rsqrtf(var + EPSF);
    }
    __syncthreads();
    float mean = smean, inv = sinv;
    for (int i = tid; i < N; i += 256) yr[i] = (__bf16)((xr[i] - mean) * inv * w[i]);
}

// ---------------------------------------------------------------------------
// Per-token prep: Kc[row] = bf16(concat(LN(kva[:512])*w, rope(kva[512:576])))
// kva row stride ld; rope q_pe in place inside bf16 q.
// ---------------------------------------------------------------------------
__global__ __launch_bounds__(256) void prep_kernel(
    const float* __restrict__ kva, int ld, const float* __restrict__ kvw,
    const float* __restrict__ cosb, const float* __restrict__ sinb,
    __bf16* __restrict__ Kc, __bf16* __restrict__ q)
{
    long long row = blockIdx.x;
    const float* kr = kva + row * ld;
    const float* cr = cosb + row * ROPED;
    const float* sr = sinb + row * ROPED;
    int tid = threadIdx.x;
    float v0 = kr[tid], v1 = kr[tid + 256];
    float s = v0 + v1, ss = v0 * v0 + v1 * v1;
#pragma unroll
    for (int off = 32; off > 0; off >>= 1) { s += __shfl_down(s, off); ss += __shfl_down(ss, off); }
    __shared__ float rs[4], rss[4];
    __shared__ float smean, sinv;
    int wave = tid >> 6, lane = tid & 63;
    if (lane == 0) { rs[wave] = s; rss[wave] = ss; }
    __syncthreads();
    if (tid == 0) {
        float S = rs[0] + rs[1] + rs[2] + rs[3];
        float Q = rss[0] + rss[1] + rss[2] + rss[3];
        float mean = S / KVLR;
        float var = Q / KVLR - mean * mean;
        smean = mean; sinv = rsqrtf(var + EPSF);
    }
    __syncthreads();
    float mean = smean, inv = sinv;
    __bf16* kc = Kc + row * 576;
    kc[tid]       = (__bf16)((v0 - mean) * inv * kvw[tid]);
    kc[tid + 256] = (__bf16)((v1 - mean) * inv * kvw[tid + 256]);
    if (tid < 32) {
        float x1 = kr[KVLR + tid], x2 = kr[KVLR + 32 + tid];
        kc[512 + tid]      = (__bf16)(x1 * cr[tid] - x2 * sr[tid]);
        kc[512 + 32 + tid] = (__bf16)(x2 * cr[32 + tid] + x1 * sr[32 + tid]);
    }
    __bf16* qr = q + row * (NHD * QKD);
#pragma unroll
    for (int j = 0; j < 2; ++j) {
        int idx = tid + j * 256;
        int h = idx >> 5, p = idx & 31;
        __bf16* base = qr + h * QKD + NOPE;
        float x1 = (float)base[p], x2 = (float)base[32 + p];
        base[p]      = (__bf16)(x1 * cr[p] - x2 * sr[p]);
        base[32 + p] = (__bf16)(x2 * cr[32 + p] + x1 * sr[32 + p]);
    }
}

// ---------------------------------------------------------------------------
// Qc bf16 [B][NH][S][576] = concat(qlat_b, roped q_pe bf16)
// ---------------------------------------------------------------------------
__global__ __launch_bounds__(256) void qcast_kernel(
    const __bf16* __restrict__ qlat, const __bf16* __restrict__ qb,
    __bf16* __restrict__ Qc)
{
    long long row = blockIdx.x;           // b*S + s
    int b = (int)(row >> 10), s = (int)(row & 1023);
    int tid = threadIdx.x;
    for (int i = tid; i < NHD * 576; i += 256) {
        int h = i / 576, c = i - h * 576;
        __bf16 v = (c < 512) ? qlat[row * (NHD * 512) + h * 512 + c]
                             : qb[row * (NHD * QKD) + h * QKD + NOPE + (c - 512)];
        Qc[(((size_t)(b * NHD + h)) * SS + s) * 576 + c] = v;
    }
}

// ---------------------------------------------------------------------------
// Flash MLA v6: 512 threads / 8 waves. Waves 0-3 = q-tile (15-p), waves
// 4-7 = q-tile p -> every block stages 32-2p k-tiles, per-SIMD MFMA visits
// ~constant (32-34). K/V staged via global_load_lds in FRAGMENT ORDER:
//   Ksf[c=2*kc+h][lane][8] = K[k0+h*16+ln][kc*32+quad*8+j]   (36 KB)
//   Vsf[nt][lane][8]       = V^T[nt*16+ln][k0+quad*8+j]      (32 KB)
// -> every ds_read_b128 is base+lane*16B: conflict-free. Waves 0-3 stage
// Ks (9 chunks each), waves 4-7 stage Vs (8 chunks each). 2 barriers/tile.
// ---------------------------------------------------------------------------
__global__ __launch_bounds__(512, 2) void flash_kernel(
    const __bf16* __restrict__ Qc, const __bf16* __restrict__ Kc,
    const __bf16* __restrict__ Vt, __bf16* __restrict__ ctx)
{
    __shared__ __bf16 Ksf[36 * 512];   // 36,864 B
    __shared__ __bf16 Vsf[32 * 512];   // 32,768 B
    __shared__ __bf16 Pb[8][16][32];   //  8,192 B  -> 77,824 total
    const int p = blockIdx.x;          // 0..7
    const int h = blockIdx.y, b = blockIdx.z;
    const int tid = threadIdx.x;
    const int w = tid >> 6, lane = tid & 63, quad = lane >> 4, ln = lane & 15;
    const int grp = w >> 2;                       // 0 = long tile, 1 = short
    const int qt = grp ? p : (15 - p);
    const int strip = qt * 64 + (w & 3) * 16;     // this wave's 16 q-rows
    const int ktc = 2 * (15 - p) + 2;             // staged k-tiles (covers long)
    const int myqmax = strip + 15;

    const size_t kbase = (size_t)b * SS * 576;
    const size_t vbase = (size_t)b * 512 * 1024;
    const float SCL = 0.07216878364870323f * 1.4426950408889634f;  // scale*log2e

    // Q fragments for this wave's strip
    const size_t qoff = ((size_t)(b * NHD + h) * SS + (size_t)(strip + ln)) * 576;
    bf16x8 qf[18];
#pragma unroll
    for (int kc = 0; kc < 18; ++kc)
        qf[kc] = *(const bf16x8*)(Qc + qoff + kc * 32 + quad * 8);

    f32x4 O[32];
#pragma unroll
    for (int nt = 0; nt < 32; ++nt) O[nt] = (f32x4){0.f, 0.f, 0.f, 0.f};
    float mrun[4] = {-1e30f, -1e30f, -1e30f, -1e30f};
    float lrun[4] = {0.f, 0.f, 0.f, 0.f};

#pragma unroll 1
    for (int kt = 0; kt < ktc; ++kt) {
        const int k0 = kt * 32;
        __syncthreads();                       // prev tile's LDS reads done
        if (w < 4) {                           // stage K fragments (9 chunks)
#pragma unroll
            for (int i = 0; i < 9; ++i) {
                const int c = w * 9 + i;       // 0..35
                const int kc = c >> 1, hh = c & 1;
                const __bf16* g = Kc + kbase + (size_t)(k0 + hh * 16 + ln) * 576
                                  + kc * 32 + quad * 8;
                gload_lds16(g, &Ksf[c * 512]);
            }
        } else {                               // stage V^T fragments (8 chunks)
#pragma unroll
            for (int i = 0; i < 8; ++i) {
                const int c = (w - 4) * 8 + i; // 0..31
                const __bf16* g = Vt + vbase + (size_t)(c * 16 + ln) * 1024
                                  + k0 + quad * 8;
                gload_lds16(g, &Vsf[c * 512]);
            }
        }
        __syncthreads();                       // staging complete (vmcnt drain)

        if (k0 <= myqmax) {                    // wave-uniform activity guard
            f32x4 s0 = (f32x4){0.f, 0.f, 0.f, 0.f};
            f32x4 s1 = (f32x4){0.f, 0.f, 0.f, 0.f};
#pragma unroll
            for (int kc = 0; kc < 18; ++kc) {
                bf16x8 kf0 = *(const bf16x8*)&Ksf[(2 * kc) * 512 + lane * 8];
                bf16x8 kf1 = *(const bf16x8*)&Ksf[(2 * kc + 1) * 512 + lane * 8];
                s0 = __builtin_amdgcn_mfma_f32_16x16x32_bf16(qf[kc], kf0, s0, 0, 0, 0);
                s1 = __builtin_amdgcn_mfma_f32_16x16x32_bf16(qf[kc], kf1, s1, 0, 0, 0);
            }

            const bool diag = (k0 + 31 > strip);
            float alpha[4];
#pragma unroll
            for (int r = 0; r < 4; ++r) {
                float v0 = s0[r] * SCL, v1 = s1[r] * SCL;
                if (diag) {
                    int qrow = strip + quad * 4 + r;
                    if (k0 + ln > qrow)      v0 = -1e30f;
                    if (k0 + 16 + ln > qrow) v1 = -1e30f;
                }
                float mx = fmaxf(v0, v1);
#pragma unroll
                for (int off = 1; off < 16; off <<= 1) mx = fmaxf(mx, __shfl_xor(mx, off));
                float mnew = fmaxf(mrun[r], mx);
                alpha[r] = __builtin_amdgcn_exp2f(mrun[r] - mnew);
                float p0 = __builtin_amdgcn_exp2f(v0 - mnew);
                float p1 = __builtin_amdgcn_exp2f(v1 - mnew);
                float rsum = p0 + p1;
#pragma unroll
                for (int off = 1; off < 16; off <<= 1) rsum += __shfl_xor(rsum, off);
                lrun[r] = lrun[r] * alpha[r] + rsum;
                mrun[r] = mnew;
                Pb[w][quad * 4 + r][ln]      = (__bf16)p0;
                Pb[w][quad * 4 + r][16 + ln] = (__bf16)p1;
            }
#pragma unroll
            for (int nt = 0; nt < 32; ++nt) {
#pragma unroll
                for (int r = 0; r < 4; ++r) O[nt][r] *= alpha[r];
            }
            bf16x8 pf = *(const bf16x8*)&Pb[w][ln][quad * 8];  // per-wave lgkm wait
#pragma unroll
            for (int nt = 0; nt < 32; ++nt) {
                bf16x8 vf = *(const bf16x8*)&Vsf[nt * 512 + lane * 8];
                O[nt] = __builtin_amdgcn_mfma_f32_16x16x32_bf16(pf, vf, O[nt], 0, 0, 0);
            }
        }
    }

    // epilogue: normalize, store bf16 ctx [B,S,NH*512]
#pragma unroll
    for (int r = 0; r < 4; ++r) {
        float inv = 1.f / lrun[r];
        size_t row = (size_t)b * SS + (size_t)(strip + quad * 4 + r);
        __bf16* op = ctx + (row * NHD + h) * 512;
#pragma unroll
        for (int nt = 0; nt < 32; ++nt)
            op[nt * 16 + ln] = (__bf16)(O[nt][r] * inv);
    }
}

// ---------------------------------------------------------------------------
extern "C" void kernel_launch(void* const* d_in, const int* in_sizes, int n_in,
                              void* d_out, int out_size, void* d_ws, size_t ws_size,
                              hipStream_t stream)
{
    const float* hidden    = (const float*)d_in[0];
    const float* cosb      = (const float*)d_in[1];
    const float* sinb      = (const float*)d_in[2];
    const float* w_qa      = (const float*)d_in[3];
    const float* q_a_ln_w  = (const float*)d_in[4];
    const float* w_qb      = (const float*)d_in[5];
    const float* w_kva     = (const float*)d_in[6];
    const float* kv_a_ln_w = (const float*)d_in[7];
    const float* W_UK_T    = (const float*)d_in[8];
    const float* W_UV      = (const float*)d_in[9];
    const float* w_o       = (const float*)d_in[10];
    float* out = (float*)d_out;

    const int M = BB * SS;  // 2048
    float* qakva = (float*)d_ws;                      // M x 2176 fp32
    __bf16* Xb    = (__bf16*)(qakva + (size_t)M * NCOMB);
    __bf16* qab   = Xb    + (size_t)M * HH;           // M*1536
    __bf16* qb    = qab   + (size_t)M * QLR;          // M*3072
    __bf16* Kc    = qb    + (size_t)M * NHD * QKD;    // M*576
    __bf16* Qc    = Kc    + (size_t)M * 576;          // M*9216
    __bf16* qlatb = Qc    + (size_t)M * NHD * 576;    // M*8192
    __bf16* ctxb  = qlatb + (size_t)M * NHD * KVLR;   // M*8192
    __bf16* ohb   = ctxb  + (size_t)M * NHD * KVLR;   // M*2048
    __bf16* Vt    = ohb   + (size_t)M * HH;           // 2*512*1024
    __bf16* w_cmb = Vt    + (size_t)BB * 512 * SS;    // 2176*2048
    __bf16* w_qbb = w_cmb + (size_t)NCOMB * HH;       // 3072*1536
    __bf16* Wkb   = w_qbb + (size_t)NHD * QKD * QLR;  // 16*512*128
    __bf16* Wvb   = Wkb   + (size_t)NHD * KVLR * NOPE;// 16*128*512
    __bf16* w_ob  = Wvb   + (size_t)NHD * VDIM * KVLR;// 2048*2048

    dim3 blk(256);

    // --- casts ---
    castf2b<<<dim3((M * HH) / 1024), blk, 0, stream>>>(hidden, Xb, M * HH);
    cast_comb<<<dim3((NCOMB * HH) / 1024), blk, 0, stream>>>(w_qa, w_kva, w_cmb);
    castf2b<<<dim3((NHD * QKD * QLR) / 1024), blk, 0, stream>>>(w_qb, w_qbb, NHD * QKD * QLR);
    castf2b<<<dim3((HH * HH) / 1024), blk, 0, stream>>>(w_o, w_ob, HH * HH);
    transpose_cast<<<dim3(KVLR / 32, NOPE / 32, NHD), blk, 0, stream>>>(W_UK_T, Wkb, NOPE, KVLR);
    transpose_cast<<<dim3(VDIM / 32, KVLR / 32, NHD), blk, 0, stream>>>(W_UV, Wvb, KVLR, VDIM);

    // 1+4 fused: qakva = Xb @ [w_qa; w_kva]^T   (2048 x 2176 x 2048)
    gemm_mfma<false><<<dim3(NCOMB / 128, M / 128, 1), blk, 0, stream>>>(
        Xb, w_cmb, qakva, M, NCOMB, HH, HH, HH, NCOMB, 0, 0, 0);
    // 2. qab = bf16(LN(qakva[:, :1536]))
    ln_kernel<<<dim3(M), blk, 0, stream>>>(qakva, q_a_ln_w, qab, QLR, NCOMB);
    // 3. qb = qab @ w_qb^T (bf16)              (2048 x 3072 x 1536)
    gemm_mfma<true><<<dim3(NHD * QKD / 128, M / 128, 1), blk, 0, stream>>>(
        qab, w_qbb, qb, M, NHD * QKD, QLR, QLR, QLR, NHD * QKD, 0, 0, 0);
    // 5. Kc = [LN(kv_c), rope(k_pe)] bf16; rope q_pe in place (bf16)
    prep_kernel<<<dim3(M), blk, 0, stream>>>(qakva + QLR, NCOMB, kv_a_ln_w,
                                             cosb, sinb, Kc, qb);
    // 5b. Vt = transpose(Kc[:, :512])
    transpose_kc<<<dim3(SS / 32, 512 / 32, BB), blk, 0, stream>>>(Kc, Vt);
    // 6. qlatb[h] = q_nope[h] @ Wkb[h]^T       (16 x [2048 x 512 x 128])
    gemm_mfma<true><<<dim3(KVLR / 128, M / 128, NHD), blk, 0, stream>>>(
        qb, Wkb, qlatb, M, KVLR, NOPE,
        NHD * QKD, NOPE, NHD * KVLR,
        (long long)QKD, (long long)KVLR * NOPE, (long long)KVLR);
    // 7. Qc = concat(qlatb, roped q_pe), layout [B,NH,S,576]
    qcast_kernel<<<dim3(M), blk, 0, stream>>>(qlatb, qb, Qc);
    // 8. flash attention -> ctx bf16; 256 balanced 8-wave blocks
    flash_kernel<<<dim3(8, NHD, BB), dim3(512), 0, stream>>>(Qc, Kc, Vt, ctxb);
    // 9. ohb[h] = ctx[h] @ Wvb[h]^T            (16 x [2048 x 128 x 512])
    gemm_mfma<true><<<dim3(VDIM / 128, M / 128, NHD), blk, 0, stream>>>(
        ctxb, Wvb, ohb, M, VDIM, KVLR,
        NHD * KVLR, KVLR, NHD * VDIM,
        (long long)KVLR, (long long)VDIM * KVLR, (long long)VDIM);
    // 10. out = ohb @ w_o^T (fp32)             (2048 x 2048 x 2048)
    gemm_mfma<false><<<dim3(HH / 128, M / 128, 1), blk, 0, stream>>>(
        ohb, w_ob, out, M, HH, NHD * VDIM, NHD * VDIM, NHD * VDIM, HH, 0, 0, 0);
}

// Round 7
// 439.373 us; speedup vs baseline: 1.7649x; 1.2775x over previous
//
#include <hip/hip_runtime.h>
#include <hip/hip_bf16.h>
#include <math.h>

#define BB 2
#define SS 1024
#define HH 2048
#define NHD 16
#define NOPE 128
#define ROPED 64
#define VDIM 128
#define QKD 192
#define QLR 1536
#define KVLR 512
#define EPSF 1e-5f
#define NCOMB 2176   // QLR + 576 kv + 64 pad

typedef __bf16 bf16x8 __attribute__((ext_vector_type(8)));
typedef float  f32x4  __attribute__((ext_vector_type(4)));

__device__ __forceinline__ void gload_lds16(const __bf16* g, __bf16* l) {
    __builtin_amdgcn_global_load_lds(
        (const __attribute__((address_space(1))) void*)g,
        (__attribute__((address_space(3))) void*)l, 16, 0, 0);
}

// ---------------------------------------------------------------------------
// MFMA bf16 GEMM: C[M,N] = A[M,K] @ B[N,K]^T (m97 structure, validated R3).
// ---------------------------------------------------------------------------
template<bool OUT_BF16>
__global__ __launch_bounds__(256, 2) void gemm_mfma(
    const __bf16* __restrict__ A, const __bf16* __restrict__ B, void* __restrict__ Cv,
    int M, int N, int K, int lda, int ldb, int ldc,
    long long sA, long long sB, long long sC)
{
    __shared__ __bf16 As[128][32];
    __shared__ __bf16 Bs[128][32];
    const __bf16* Ab = A + (long long)blockIdx.z * sA;
    const __bf16* Bb = B + (long long)blockIdx.z * sB;
    const int tid = threadIdx.x;
    const int w = tid >> 6, lane = tid & 63, quad = lane >> 4, ln = lane & 15;
    const int m0 = blockIdx.y * 128, n0 = blockIdx.x * 128;
    const int wm = (w >> 1) * 64, wn = (w & 1) * 64;
    const int srow = tid >> 2, schunk = (tid & 3) * 8;

    f32x4 acc[4][4];
#pragma unroll
    for (int i = 0; i < 4; ++i)
#pragma unroll
        for (int j = 0; j < 4; ++j) acc[i][j] = (f32x4){0.f, 0.f, 0.f, 0.f};

    const __bf16* gA0 = Ab + (size_t)(m0 + srow) * lda + schunk;
    const __bf16* gA1 = gA0 + (size_t)64 * lda;
    const __bf16* gB0 = Bb + (size_t)(n0 + srow) * ldb + schunk;
    const __bf16* gB1 = gB0 + (size_t)64 * ldb;
    __bf16* lA0 = &As[w * 16][0];
    __bf16* lA1 = &As[64 + w * 16][0];
    __bf16* lB0 = &Bs[w * 16][0];
    __bf16* lB1 = &Bs[64 + w * 16][0];

    for (int k0 = 0; k0 < K; k0 += 32) {
        __syncthreads();
        gload_lds16(gA0 + k0, lA0);
        gload_lds16(gA1 + k0, lA1);
        gload_lds16(gB0 + k0, lB0);
        gload_lds16(gB1 + k0, lB1);
        __syncthreads();
        bf16x8 af[4], bfr[4];
#pragma unroll
        for (int mi = 0; mi < 4; ++mi)
            af[mi] = *(const bf16x8*)&As[wm + mi * 16 + ln][quad * 8];
#pragma unroll
        for (int ni = 0; ni < 4; ++ni)
            bfr[ni] = *(const bf16x8*)&Bs[wn + ni * 16 + ln][quad * 8];
#pragma unroll
        for (int mi = 0; mi < 4; ++mi)
#pragma unroll
            for (int ni = 0; ni < 4; ++ni)
                acc[mi][ni] = __builtin_amdgcn_mfma_f32_16x16x32_bf16(
                    af[mi], bfr[ni], acc[mi][ni], 0, 0, 0);
    }
    if (OUT_BF16) {
        __bf16* Cb = (__bf16*)Cv + (long long)blockIdx.z * sC;
#pragma unroll
        for (int mi = 0; mi < 4; ++mi)
#pragma unroll
            for (int r = 0; r < 4; ++r) {
                size_t row = (size_t)(m0 + wm + mi * 16 + quad * 4 + r);
#pragma unroll
                for (int ni = 0; ni < 4; ++ni)
                    Cb[row * ldc + (n0 + wn + ni * 16 + ln)] = (__bf16)acc[mi][ni][r];
            }
    } else {
        float* Cb = (float*)Cv + (long long)blockIdx.z * sC;
#pragma unroll
        for (int mi = 0; mi < 4; ++mi)
#pragma unroll
            for (int r = 0; r < 4; ++r) {
                size_t row = (size_t)(m0 + wm + mi * 16 + quad * 4 + r);
#pragma unroll
                for (int ni = 0; ni < 4; ++ni)
                    Cb[row * ldc + (n0 + wn + ni * 16 + ln)] = acc[mi][ni][r];
            }
    }
}

// ---------------------------------------------------------------------------
// Causal scores GEMM: Sc[z] = (Qc[z] @ Kc[b]^T) * scale, bf16 out, diagonal
// masked to -1e30. z = b*16+h. Upper tiles (nt>mt) early-exit (never written,
// never read downstream).
// ---------------------------------------------------------------------------
__global__ __launch_bounds__(256, 2) void gemm_scores(
    const __bf16* __restrict__ Qc, const __bf16* __restrict__ Kc,
    __bf16* __restrict__ Sc)
{
    const int nt = blockIdx.x, mt = blockIdx.y, z = blockIdx.z;
    if (nt > mt) return;
    const int b = z >> 4;
    __shared__ __bf16 As[128][32];
    __shared__ __bf16 Bs[128][32];
    const __bf16* Ab = Qc + (size_t)z * SS * 576;
    const __bf16* Bb = Kc + (size_t)b * SS * 576;
    __bf16* Cb = Sc + (size_t)z * SS * SS;
    const int tid = threadIdx.x;
    const int w = tid >> 6, lane = tid & 63, quad = lane >> 4, ln = lane & 15;
    const int m0 = mt * 128, n0 = nt * 128;
    const int wm = (w >> 1) * 64, wn = (w & 1) * 64;
    const int srow = tid >> 2, schunk = (tid & 3) * 8;

    f32x4 acc[4][4];
#pragma unroll
    for (int i = 0; i < 4; ++i)
#pragma unroll
        for (int j = 0; j < 4; ++j) acc[i][j] = (f32x4){0.f, 0.f, 0.f, 0.f};

    const __bf16* gA0 = Ab + (size_t)(m0 + srow) * 576 + schunk;
    const __bf16* gA1 = gA0 + (size_t)64 * 576;
    const __bf16* gB0 = Bb + (size_t)(n0 + srow) * 576 + schunk;
    const __bf16* gB1 = gB0 + (size_t)64 * 576;
    __bf16* lA0 = &As[w * 16][0];
    __bf16* lA1 = &As[64 + w * 16][0];
    __bf16* lB0 = &Bs[w * 16][0];
    __bf16* lB1 = &Bs[64 + w * 16][0];

    for (int k0 = 0; k0 < 576; k0 += 32) {
        __syncthreads();
        gload_lds16(gA0 + k0, lA0);
        gload_lds16(gA1 + k0, lA1);
        gload_lds16(gB0 + k0, lB0);
        gload_lds16(gB1 + k0, lB1);
        __syncthreads();
        bf16x8 af[4], bfr[4];
#pragma unroll
        for (int mi = 0; mi < 4; ++mi)
            af[mi] = *(const bf16x8*)&As[wm + mi * 16 + ln][quad * 8];
#pragma unroll
        for (int ni = 0; ni < 4; ++ni)
            bfr[ni] = *(const bf16x8*)&Bs[wn + ni * 16 + ln][quad * 8];
#pragma unroll
        for (int mi = 0; mi < 4; ++mi)
#pragma unroll
            for (int ni = 0; ni < 4; ++ni)
                acc[mi][ni] = __builtin_amdgcn_mfma_f32_16x16x32_bf16(
                    af[mi], bfr[ni], acc[mi][ni], 0, 0, 0);
    }
    const float SCL2 = 0.07216878364870323f * 1.4426950408889634f;  // scale*log2e
#pragma unroll
    for (int mi = 0; mi < 4; ++mi)
#pragma unroll
        for (int r = 0; r < 4; ++r) {
            int row = m0 + wm + mi * 16 + quad * 4 + r;
#pragma unroll
            for (int ni = 0; ni < 4; ++ni) {
                int col = n0 + wn + ni * 16 + ln;
                float v = acc[mi][ni][r] * SCL2;
                if (col > row) v = -1e30f;
                Cb[(size_t)row * SS + col] = (__bf16)v;
            }
        }
}

// ---------------------------------------------------------------------------
// Row softmax (exp2 domain, scores pre-scaled by scale*log2e). One wave per
// row, shfl-only reductions. Processes cols [0, diag_tile_end); normalizes
// in place. Upper region untouched (never read by PV).
// ---------------------------------------------------------------------------
__global__ __launch_bounds__(256) void softmax_kernel(__bf16* __restrict__ Sc)
{
    const int z = blockIdx.y;
    const int w = threadIdx.x >> 6, lane = threadIdx.x & 63;
    const int r = blockIdx.x * 4 + w;
    __bf16* row = Sc + (size_t)z * SS * SS + (size_t)r * SS;
    const int ncols = ((r >> 7) + 1) << 7;
    const int i0 = lane * 8, i1 = i0 + 512;
    const bool a0 = i0 < ncols, a1 = i1 < ncols;
    float v[16];
    float lmax = -1e30f;
    if (a0) {
        bf16x8 c = *(const bf16x8*)(row + i0);
#pragma unroll
        for (int j = 0; j < 8; ++j) { v[j] = (float)c[j]; lmax = fmaxf(lmax, v[j]); }
    }
    if (a1) {
        bf16x8 c = *(const bf16x8*)(row + i1);
#pragma unroll
        for (int j = 0; j < 8; ++j) { v[8 + j] = (float)c[j]; lmax = fmaxf(lmax, v[8 + j]); }
    }
#pragma unroll
    for (int off = 1; off < 64; off <<= 1) lmax = fmaxf(lmax, __shfl_xor(lmax, off));
    float lsum = 0.f;
    if (a0) {
#pragma unroll
        for (int j = 0; j < 8; ++j) { v[j] = __builtin_amdgcn_exp2f(v[j] - lmax); lsum += v[j]; }
    }
    if (a1) {
#pragma unroll
        for (int j = 0; j < 8; ++j) { v[8 + j] = __builtin_amdgcn_exp2f(v[8 + j] - lmax); lsum += v[8 + j]; }
    }
#pragma unroll
    for (int off = 1; off < 64; off <<= 1) lsum += __shfl_xor(lsum, off);
    const float inv = 1.f / lsum;
    if (a0) {
        bf16x8 c;
#pragma unroll
        for (int j = 0; j < 8; ++j) c[j] = (__bf16)(v[j] * inv);
        *(bf16x8*)(row + i0) = c;
    }
    if (a1) {
        bf16x8 c;
#pragma unroll
        for (int j = 0; j < 8; ++j) c[j] = (__bf16)(v[8 + j] * inv);
        *(bf16x8*)(row + i1) = c;
    }
}

// ---------------------------------------------------------------------------
// PV GEMM: ctx[b, m, h*512+n] = P[z] @ V[b]  (B operand = Vt[b][n][k]).
// Causal k-bound: K_eff = (mt+1)*128.
// ---------------------------------------------------------------------------
__global__ __launch_bounds__(256, 2) void gemm_pv(
    const __bf16* __restrict__ Sc, const __bf16* __restrict__ Vt,
    __bf16* __restrict__ ctx)
{
    const int nt = blockIdx.x, mt = blockIdx.y, z = blockIdx.z;
    const int b = z >> 4, h = z & 15;
    const int Keff = (mt + 1) * 128;
    __shared__ __bf16 As[128][32];
    __shared__ __bf16 Bs[128][32];
    const __bf16* Ab = Sc + (size_t)z * SS * SS;
    const __bf16* Bb = Vt + (size_t)b * 512 * 1024;
    const int tid = threadIdx.x;
    const int w = tid >> 6, lane = tid & 63, quad = lane >> 4, ln = lane & 15;
    const int m0 = mt * 128, n0 = nt * 128;
    const int wm = (w >> 1) * 64, wn = (w & 1) * 64;
    const int srow = tid >> 2, schunk = (tid & 3) * 8;

    f32x4 acc[4][4];
#pragma unroll
    for (int i = 0; i < 4; ++i)
#pragma unroll
        for (int j = 0; j < 4; ++j) acc[i][j] = (f32x4){0.f, 0.f, 0.f, 0.f};

    const __bf16* gA0 = Ab + (size_t)(m0 + srow) * SS + schunk;
    const __bf16* gA1 = gA0 + (size_t)64 * SS;
    const __bf16* gB0 = Bb + (size_t)(n0 + srow) * 1024 + schunk;
    const __bf16* gB1 = gB0 + (size_t)64 * 1024;
    __bf16* lA0 = &As[w * 16][0];
    __bf16* lA1 = &As[64 + w * 16][0];
    __bf16* lB0 = &Bs[w * 16][0];
    __bf16* lB1 = &Bs[64 + w * 16][0];

    for (int k0 = 0; k0 < Keff; k0 += 32) {
        __syncthreads();
        gload_lds16(gA0 + k0, lA0);
        gload_lds16(gA1 + k0, lA1);
        gload_lds16(gB0 + k0, lB0);
        gload_lds16(gB1 + k0, lB1);
        __syncthreads();
        bf16x8 af[4], bfr[4];
#pragma unroll
        for (int mi = 0; mi < 4; ++mi)
            af[mi] = *(const bf16x8*)&As[wm + mi * 16 + ln][quad * 8];
#pragma unroll
        for (int ni = 0; ni < 4; ++ni)
            bfr[ni] = *(const bf16x8*)&Bs[wn + ni * 16 + ln][quad * 8];
#pragma unroll
        for (int mi = 0; mi < 4; ++mi)
#pragma unroll
            for (int ni = 0; ni < 4; ++ni)
                acc[mi][ni] = __builtin_amdgcn_mfma_f32_16x16x32_bf16(
                    af[mi], bfr[ni], acc[mi][ni], 0, 0, 0);
    }
#pragma unroll
    for (int mi = 0; mi < 4; ++mi)
#pragma unroll
        for (int r = 0; r < 4; ++r) {
            int row = m0 + wm + mi * 16 + quad * 4 + r;
            __bf16* op = ctx + (size_t)(b * SS + row) * (NHD * KVLR) + h * KVLR;
#pragma unroll
            for (int ni = 0; ni < 4; ++ni)
                op[n0 + wn + ni * 16 + ln] = (__bf16)acc[mi][ni][r];
        }
}

// ---------------------------------------------------------------------------
// Cast helpers
// ---------------------------------------------------------------------------
__global__ __launch_bounds__(256) void castf2b(const float* __restrict__ in,
                                               __bf16* __restrict__ out, int n)
{
    int i = (blockIdx.x * 256 + threadIdx.x) * 4;
    if (i < n) {
        float4 v = *(const float4*)(in + i);
        out[i] = (__bf16)v.x; out[i + 1] = (__bf16)v.y;
        out[i + 2] = (__bf16)v.z; out[i + 3] = (__bf16)v.w;
    }
}

// combined [w_qa(1536); w_kva(576); pad(64)] x 2048 -> bf16
__global__ __launch_bounds__(256) void cast_comb(const float* __restrict__ wqa,
                                                 const float* __restrict__ wkva,
                                                 __bf16* __restrict__ out)
{
    int idx = (blockIdx.x * 256 + threadIdx.x) * 4;
    int row = idx >> 11, col = idx & 2047;
    const float* src;
    if (row < 1536)      src = wqa + (size_t)row * 2048 + col;
    else if (row < 2112) src = wkva + (size_t)(row - 1536) * 2048 + col;
    else {
        out[idx] = (__bf16)0.f; out[idx + 1] = (__bf16)0.f;
        out[idx + 2] = (__bf16)0.f; out[idx + 3] = (__bf16)0.f;
        return;
    }
    float4 v = *(const float4*)src;
    out[idx] = (__bf16)v.x; out[idx + 1] = (__bf16)v.y;
    out[idx + 2] = (__bf16)v.z; out[idx + 3] = (__bf16)v.w;
}

// batched transpose-cast: in[z][R][C] fp32 -> out[z][C][R] bf16
__global__ __launch_bounds__(256) void transpose_cast(const float* __restrict__ in,
                                                      __bf16* __restrict__ out,
                                                      int R, int C)
{
    __shared__ float t[32][33];
    in  += (size_t)blockIdx.z * R * C;
    out += (size_t)blockIdx.z * R * C;
    int c0 = blockIdx.x * 32, r0 = blockIdx.y * 32;
    int tx = threadIdx.x & 31, ty = threadIdx.x >> 5;
#pragma unroll
    for (int i = 0; i < 4; ++i) {
        int r = ty + i * 8;
        t[r][tx] = in[(size_t)(r0 + r) * C + c0 + tx];
    }
    __syncthreads();
#pragma unroll
    for (int i = 0; i < 4; ++i) {
        int rr = ty + i * 8;
        out[(size_t)(c0 + rr) * R + r0 + tx] = (__bf16)t[tx][rr];
    }
}

// Kc[b][k][f<512] bf16 -> Vt[b][f][k] bf16 (key-contiguous V)
__global__ __launch_bounds__(256) void transpose_kc(const __bf16* __restrict__ Kc,
                                                    __bf16* __restrict__ Vt)
{
    __shared__ __bf16 t[32][33];
    int b = blockIdx.z;
    int k0 = blockIdx.x * 32, f0 = blockIdx.y * 32;
    int tx = threadIdx.x & 31, ty = threadIdx.x >> 5;   // ty 0..7
    const __bf16* src = Kc + (size_t)b * SS * 576;
#pragma unroll
    for (int i = 0; i < 4; ++i)
        t[ty + i * 8][tx] = src[(size_t)(k0 + ty + i * 8) * 576 + f0 + tx];
    __syncthreads();
    __bf16* dst = Vt + (size_t)b * 512 * 1024;
#pragma unroll
    for (int i = 0; i < 4; ++i)
        dst[(size_t)(f0 + ty + i * 8) * 1024 + k0 + tx] = t[tx][ty + i * 8];
}

// ---------------------------------------------------------------------------
// LayerNorm fp32 in (row stride ldx) -> bf16 out (row stride N).
// ---------------------------------------------------------------------------
__global__ __launch_bounds__(256) void ln_kernel(const float* __restrict__ x,
                                                 const float* __restrict__ w,
                                                 __bf16* __restrict__ y, int N, int ldx)
{
    long long row = blockIdx.x;
    const float* xr = x + row * ldx;
    __bf16* yr = y + row * N;
    int tid = threadIdx.x;
    float s = 0.f, ss = 0.f;
    for (int i = tid; i < N; i += 256) { float v = xr[i]; s += v; ss += v * v; }
#pragma unroll
    for (int off = 32; off > 0; off >>= 1) { s += __shfl_down(s, off); ss += __shfl_down(ss, off); }
    __shared__ float rs[4], rss[4];
    __shared__ float smean, sinv;
    int wave = tid >> 6, lane = tid & 63;
    if (lane == 0) { rs[wave] = s; rss[wave] = ss; }
    __syncthreads();
    if (tid == 0) {
        float S = rs[0] + rs[1] + rs[2] + rs[3];
        float Q = rss[0] + rss[1] + rss[2] + rss[3];
        float mean = S / N;
        float var = Q / N - mean * mean;
        smean = mean; sinv = rsqrtf(var + EPSF);
    }
    __syncthreads();
    float mean = smean, inv = sinv;
    for (int i = tid; i < N; i += 256) yr[i] = (__bf16)((xr[i] - mean) * inv * w[i]);
}

// ---------------------------------------------------------------------------
// Per-token prep: Kc[row] = bf16(concat(LN(kva[:512])*w, rope(kva[512:576])))
// kva row stride ld; rope q_pe in place inside bf16 q.
// ---------------------------------------------------------------------------
__global__ __launch_bounds__(256) void prep_kernel(
    const float* __restrict__ kva, int ld, const float* __restrict__ kvw,
    const float* __restrict__ cosb, const float* __restrict__ sinb,
    __bf16* __restrict__ Kc, __bf16* __restrict__ q)
{
    long long row = blockIdx.x;
    const float* kr = kva + row * ld;
    const float* cr = cosb + row * ROPED;
    const float* sr = sinb + row * ROPED;
    int tid = threadIdx.x;
    float v0 = kr[tid], v1 = kr[tid + 256];
    float s = v0 + v1, ss = v0 * v0 + v1 * v1;
#pragma unroll
    for (int off = 32; off > 0; off >>= 1) { s += __shfl_down(s, off); ss += __shfl_down(ss, off); }
    __shared__ float rs[4], rss[4];
    __shared__ float smean, sinv;
    int wave = tid >> 6, lane = tid & 63;
    if (lane == 0) { rs[wave] = s; rss[wave] = ss; }
    __syncthreads();
    if (tid == 0) {
        float S = rs[0] + rs[1] + rs[2] + rs[3];
        float Q = rss[0] + rss[1] + rss[2] + rss[3];
        float mean = S / KVLR;
        float var = Q / KVLR - mean * mean;
        smean = mean; sinv = rsqrtf(var + EPSF);
    }
    __syncthreads();
    float mean = smean, inv = sinv;
    __bf16* kc = Kc + row * 576;
    kc[tid]       = (__bf16)((v0 - mean) * inv * kvw[tid]);
    kc[tid + 256] = (__bf16)((v1 - mean) * inv * kvw[tid + 256]);
    if (tid < 32) {
        float x1 = kr[KVLR + tid], x2 = kr[KVLR + 32 + tid];
        kc[512 + tid]      = (__bf16)(x1 * cr[tid] - x2 * sr[tid]);
        kc[512 + 32 + tid] = (__bf16)(x2 * cr[32 + tid] + x1 * sr[32 + tid]);
    }
    __bf16* qr = q + row * (NHD * QKD);
#pragma unroll
    for (int j = 0; j < 2; ++j) {
        int idx = tid + j * 256;
        int h = idx >> 5, p = idx & 31;
        __bf16* base = qr + h * QKD + NOPE;
        float x1 = (float)base[p], x2 = (float)base[32 + p];
        base[p]      = (__bf16)(x1 * cr[p] - x2 * sr[p]);
        base[32 + p] = (__bf16)(x2 * cr[32 + p] + x1 * sr[32 + p]);
    }
}

// ---------------------------------------------------------------------------
// Qc bf16 [B][NH][S][576] = concat(qlat_b, roped q_pe bf16)
// ---------------------------------------------------------------------------
__global__ __launch_bounds__(256) void qcast_kernel(
    const __bf16* __restrict__ qlat, const __bf16* __restrict__ qb,
    __bf16* __restrict__ Qc)
{
    long long row = blockIdx.x;           // b*S + s
    int b = (int)(row >> 10), s = (int)(row & 1023);
    int tid = threadIdx.x;
    for (int i = tid; i < NHD * 576; i += 256) {
        int h = i / 576, c = i - h * 576;
        __bf16 v = (c < 512) ? qlat[row * (NHD * 512) + h * 512 + c]
                             : qb[row * (NHD * QKD) + h * QKD + NOPE + (c - 512)];
        Qc[(((size_t)(b * NHD + h)) * SS + s) * 576 + c] = v;
    }
}

// ---------------------------------------------------------------------------
extern "C" void kernel_launch(void* const* d_in, const int* in_sizes, int n_in,
                              void* d_out, int out_size, void* d_ws, size_t ws_size,
                              hipStream_t stream)
{
    const float* hidden    = (const float*)d_in[0];
    const float* cosb      = (const float*)d_in[1];
    const float* sinb      = (const float*)d_in[2];
    const float* w_qa      = (const float*)d_in[3];
    const float* q_a_ln_w  = (const float*)d_in[4];
    const float* w_qb      = (const float*)d_in[5];
    const float* w_kva     = (const float*)d_in[6];
    const float* kv_a_ln_w = (const float*)d_in[7];
    const float* W_UK_T    = (const float*)d_in[8];
    const float* W_UV      = (const float*)d_in[9];
    const float* w_o       = (const float*)d_in[10];
    float* out = (float*)d_out;

    const int M = BB * SS;  // 2048
    // ---- HEAD region: transient buffers, later aliased by Sc (67.1 MB) ----
    // qakva fp32 17.8MB | Xb 8MB | qab 6.3MB | qb 12.6MB | qlatb 33.6MB = 78.3MB
    float*  qakva = (float*)d_ws;
    __bf16* Xb    = (__bf16*)(qakva + (size_t)M * NCOMB);
    __bf16* qab   = Xb    + (size_t)M * HH;
    __bf16* qb    = qab   + (size_t)M * QLR;
    __bf16* qlatb = qb    + (size_t)M * NHD * QKD;
    __bf16* Sc    = (__bf16*)d_ws;                    // aliases head after qcast
    // ---- TAIL region: persistent ----
    __bf16* Kc    = qlatb + (size_t)M * NHD * KVLR;   // M*576
    __bf16* Qc    = Kc    + (size_t)M * 576;          // M*9216
    __bf16* Vt    = Qc    + (size_t)M * NHD * 576;    // 2*512*1024
    __bf16* ctxb  = Vt    + (size_t)BB * 512 * SS;    // M*8192
    __bf16* ohb   = ctxb  + (size_t)M * NHD * KVLR;   // M*2048
    __bf16* w_cmb = ohb   + (size_t)M * HH;           // 2176*2048
    __bf16* w_qbb = w_cmb + (size_t)NCOMB * HH;       // 3072*1536
    __bf16* Wkb   = w_qbb + (size_t)NHD * QKD * QLR;  // 16*512*128
    __bf16* Wvb   = Wkb   + (size_t)NHD * KVLR * NOPE;// 16*128*512
    __bf16* w_ob  = Wvb   + (size_t)NHD * VDIM * KVLR;// 2048*2048

    dim3 blk(256);

    // --- casts ---
    castf2b<<<dim3((M * HH) / 1024), blk, 0, stream>>>(hidden, Xb, M * HH);
    cast_comb<<<dim3((NCOMB * HH) / 1024), blk, 0, stream>>>(w_qa, w_kva, w_cmb);
    castf2b<<<dim3((NHD * QKD * QLR) / 1024), blk, 0, stream>>>(w_qb, w_qbb, NHD * QKD * QLR);
    castf2b<<<dim3((HH * HH) / 1024), blk, 0, stream>>>(w_o, w_ob, HH * HH);
    transpose_cast<<<dim3(KVLR / 32, NOPE / 32, NHD), blk, 0, stream>>>(W_UK_T, Wkb, NOPE, KVLR);
    transpose_cast<<<dim3(VDIM / 32, KVLR / 32, NHD), blk, 0, stream>>>(W_UV, Wvb, KVLR, VDIM);

    // 1+4 fused: qakva = Xb @ [w_qa; w_kva]^T   (2048 x 2176 x 2048)
    gemm_mfma<false><<<dim3(NCOMB / 128, M / 128, 1), blk, 0, stream>>>(
        Xb, w_cmb, qakva, M, NCOMB, HH, HH, HH, NCOMB, 0, 0, 0);
    // 2. qab = bf16(LN(qakva[:, :1536]))
    ln_kernel<<<dim3(M), blk, 0, stream>>>(qakva, q_a_ln_w, qab, QLR, NCOMB);
    // 3. qb = qab @ w_qb^T (bf16)              (2048 x 3072 x 1536)
    gemm_mfma<true><<<dim3(NHD * QKD / 128, M / 128, 1), blk, 0, stream>>>(
        qab, w_qbb, qb, M, NHD * QKD, QLR, QLR, QLR, NHD * QKD, 0, 0, 0);
    // 5. Kc = [LN(kv_c), rope(k_pe)] bf16; rope q_pe in place (bf16)
    prep_kernel<<<dim3(M), blk, 0, stream>>>(qakva + QLR, NCOMB, kv_a_ln_w,
                                             cosb, sinb, Kc, qb);
    // 5b. Vt = transpose(Kc[:, :512])
    transpose_kc<<<dim3(SS / 32, 512 / 32, BB), blk, 0, stream>>>(Kc, Vt);
    // 6. qlatb[h] = q_nope[h] @ Wkb[h]^T       (16 x [2048 x 512 x 128])
    gemm_mfma<true><<<dim3(KVLR / 128, M / 128, NHD), blk, 0, stream>>>(
        qb, Wkb, qlatb, M, KVLR, NOPE,
        NHD * QKD, NOPE, NHD * KVLR,
        (long long)QKD, (long long)KVLR * NOPE, (long long)KVLR);
    // 7. Qc = concat(qlatb, roped q_pe), layout [B,NH,S,576]
    qcast_kernel<<<dim3(M), blk, 0, stream>>>(qlatb, qb, Qc);
    // 8a. Sc = causal scores (Qc @ Kc^T)*scale  [bf16, head region now dead]
    gemm_scores<<<dim3(8, 8, 32), blk, 0, stream>>>(Qc, Kc, Sc);
    // 8b. row softmax in place
    softmax_kernel<<<dim3(SS / 4, 32), blk, 0, stream>>>(Sc);
    // 8c. ctx = P @ V (causal k-bound)
    gemm_pv<<<dim3(4, 8, 32), blk, 0, stream>>>(Sc, Vt, ctxb);
    // 9. ohb[h] = ctx[h] @ Wvb[h]^T            (16 x [2048 x 128 x 512])
    gemm_mfma<true><<<dim3(VDIM / 128, M / 128, NHD), blk, 0, stream>>>(
        ctxb, Wvb, ohb, M, VDIM, KVLR,
        NHD * KVLR, KVLR, NHD * VDIM,
        (long long)KVLR, (long long)VDIM * KVLR, (long long)VDIM);
    // 10. out = ohb @ w_o^T (fp32)             (2048 x 2048 x 2048)
    gemm_mfma<false><<<dim3(HH / 128, M / 128, 1), blk, 0, stream>>>(
        ohb, w_ob, out, M, HH, NHD * VDIM, NHD * VDIM, NHD * VDIM, HH, 0, 0, 0);
}